// Round 4
// baseline (152.061 us; speedup 1.0000x reference)
//
#include <hip/hip_runtime.h>

#define NEMB 64   // K = NUM_BINS + 1
#define DIM  64   // EMB_DIM
#define NBINS 63

typedef float f32x4 __attribute__((ext_vector_type(4)));

// T[i][d] = sum_k weight[k][d] / (|i-k|+1)   (16 KB table in d_ws)
__global__ __launch_bounds__(256) void build_table_kernel(
    const float* __restrict__ weight, float* __restrict__ T) {
    const int e = blockIdx.x * 256 + threadIdx.x;  // 0..4095
    const int i = e >> 6;   // table row
    const int d = e & 63;   // dim
    float acc = 0.0f;
    #pragma unroll
    for (int k = 0; k < NEMB; ++k) {
        int diff = i - k;
        diff = diff < 0 ? -diff : diff;
        acc += weight[k * DIM + d] * (1.0f / (float)(diff + 1));
    }
    T[e] = acc;
}

// Per block: 256 rows. Phase 1: exact-compare binary search for bucket index
// (bins staged in LDS). Phase 2: 16-lane groups gather T rows straight from
// global (T = 16 KB -> L1-resident) and stream coalesced float4 stores.
__global__ __launch_bounds__(256) void emb_gather_kernel(
    const float* __restrict__ x,
    const float* __restrict__ low,
    const f32x4* __restrict__ T4,
    f32x4* __restrict__ out4,
    int n_rows) {
    __shared__ float bins_lds[NBINS];
    __shared__ int   idx_lds[256];

    const int t = threadIdx.x;
    if (t < NBINS) bins_lds[t] = low[t + 1];   // exact bin edges
    __syncthreads();

    const int base = blockIdx.x * 256;

    // Phase 1: index = #{ j : x > bins[j] } via branchless binary search
    // (strides 32+16+8+4+2+1 = 63; probes provably stay in [0,62]).
    {
        const int row = base + t;
        float xv = (row < n_rows) ? x[row] : 0.0f;
        int c = 0;
        if (xv > bins_lds[c + 31]) c += 32;
        if (xv > bins_lds[c + 15]) c += 16;
        if (xv > bins_lds[c + 7])  c += 8;
        if (xv > bins_lds[c + 3])  c += 4;
        if (xv > bins_lds[c + 1])  c += 2;
        if (xv > bins_lds[c])      c += 1;
        idx_lds[t] = c;
    }
    __syncthreads();

    const int sub   = t >> 4;   // row-group 0..15
    const int lane4 = t & 15;   // float4 slot within the 64-float row

    // Hoist all 16 indices into registers (static indexing -> VGPRs),
    // so the 16 global row-loads issue without LDS on the critical path.
    int myidx[16];
    #pragma unroll
    for (int it = 0; it < 16; ++it)
        myidx[it] = idx_lds[it * 16 + sub];

    #pragma unroll
    for (int it = 0; it < 16; ++it) {
        const int grow = base + it * 16 + sub;
        if (grow < n_rows) {
            const f32x4 v = T4[myidx[it] * 16 + lane4];   // L1/L2 hit
            __builtin_nontemporal_store(v, &out4[grow * 16 + lane4]);
        }
    }
}

extern "C" void kernel_launch(void* const* d_in, const int* in_sizes, int n_in,
                              void* d_out, int out_size, void* d_ws, size_t ws_size,
                              hipStream_t stream) {
    const float* x      = (const float*)d_in[0];   // [B*F]
    const float* low    = (const float*)d_in[1];   // [64]  (-inf, bins...)
    const float* weight = (const float*)d_in[3];   // [64*64]
    float* out = (float*)d_out;
    float* T   = (float*)d_ws;                     // 16 KB table scratch

    const int n_rows = in_sizes[0];                // B*F = 524288

    build_table_kernel<<<16, 256, 0, stream>>>(weight, T);

    const int blocks = (n_rows + 255) / 256;       // 2048
    emb_gather_kernel<<<blocks, 256, 0, stream>>>(
        x, low, (const f32x4*)T, (f32x4*)out, n_rows);
}